// Round 8
// baseline (994.786 us; speedup 1.0000x reference)
//
#include <hip/hip_runtime.h>
#include <cmath>

#define TT 256
#define KD 192
#define RINGM 127   // 128-row ring for bufA/bufC

typedef _Float16 f16;
typedef _Float16 f16x4 __attribute__((ext_vector_type(4)));
typedef _Float16 f16x8 __attribute__((ext_vector_type(8)));
typedef float    f32x4 __attribute__((ext_vector_type(4)));
typedef unsigned int u32;

#define SWZ(b,k) ((k) ^ (((b)&7)<<3))
#define MFMA16(a,bb,c) __builtin_amdgcn_mfma_f32_16x16x32_f16((a),(bb),(c),0,0,0)

// lgkm-only barrier: orders the LDS xh/fin handoff across waves WITHOUT
// draining vmcnt -- global prefetch loads and stores stay in flight across
// the barrier (T4-style). Pattern proven in learn_hip m201.
#define LBAR() do { \
  __builtin_amdgcn_sched_barrier(0); \
  asm volatile("s_waitcnt lgkmcnt(0)" ::: "memory"); \
  __builtin_amdgcn_s_barrier(); \
  __builtin_amdgcn_sched_barrier(0); \
} while (0)

__device__ __forceinline__ float sigm(float x){
  return __builtin_amdgcn_rcpf(1.0f + __expf(-x));
}
__device__ __forceinline__ float ftanh(float x){
  x = fminf(15.0f, fmaxf(-15.0f, x));
  float e = __expf(-2.0f*x);
  return (1.0f - e) * __builtin_amdgcn_rcpf(1.0f + e);
}
// tag flags: entry g holds g+1 when ready (g+1 <= 64, never the 0xAA poison)
__device__ __forceinline__ void waitflag(const u32* p, u32 v){
  while (__hip_atomic_load(p, __ATOMIC_ACQUIRE, __HIP_MEMORY_SCOPE_AGENT) != v)
    __builtin_amdgcn_s_sleep(1);
}
__device__ __forceinline__ void setflag(u32* p, u32 v){
  __hip_atomic_store(p, v, __ATOMIC_RELEASE, __HIP_MEMORY_SCOPE_AGENT);
}

// 64 blocks: blockIdx = l*16 + bg (l and l+1 are 16 apart -> same XCD).
// Stage l runs layer l's 256 steps for its 16-batch group.
// l0 -> bufA(ring,f16) -> l1 -> d_out(f32) -> {l2, l3 skip}
// l2 -> bufC(ring,f16) -> l3 -> d_out (fused projection)
// fwd flags: PER PRODUCER WAVE (4 arrays) so each wave's release orders only
// its own stores -- no block-wide vmcnt drain anywhere in the loop.
extern "C" __global__ void
__attribute__((amdgpu_flat_work_group_size(512,512), amdgpu_waves_per_eu(2,2)))
s2_pipe_kernel(const float* __restrict__ xin, const float* __restrict__ W,
               const float* __restrict__ bias, const float* __restrict__ Wa,
               const float* __restrict__ ba, float* __restrict__ out,
               f16* __restrict__ bufA, f16* __restrict__ bufC,
               u32* __restrict__ fwdf, u32* __restrict__ consf)
{
  const int tid  = threadIdx.x;
  const int wave = tid >> 6;
  const int lane = tid & 63;
  const int b    = lane & 15;
  const int g4   = lane >> 4;
  const int bg   = blockIdx.x & 15;
  const int l    = blockIdx.x >> 4;
  const int gb   = bg*16 + b;
  const int s0   = wave*16 + g4*4;
  const int d    = (l==0)?1:((l==1)?3:((l==2)?6:12));

  __shared__ f16 sxh[2][16*KD];
  __shared__ f16 scb[12*16*128];
  __shared__ f16 shb[12*16*64];
  __shared__ f16 sfin[2][16*64];

  // flag arrays: fwdf [l(0..2)][w(0..3)][bg][64], consf [ch(0..1)][w][bg][64]
  u32* myFwd = fwdf + (((l<3?l:0)*4 + (wave&3))*16 + bg)*64;      // publish (l<3)
  u32* fIn0  = fwdf + ((((l>0?l-1:0))*4 + 0)*16 + bg)*64;         // poll (l>0)
  const int pitch = 16*64;
  u32* myCons = consf + ((((l==3)?1:0)*4 + (wave&3))*16 + bg)*64; // publish (l1,l3)
  u32* cPol0  = consf + ((((l==2)?1:0)*4 + 0)*16 + bg)*64;        // poll (l0,l2)

  f16* ringOut      = (l==0) ? bufA : bufC;
  const f16* ringIn = (l==1) ? bufA : bufC;

  // ---- projection frags (l==3, waves 0-3) ----
  f16x8 aP[2]; f32x4 cbP;
  if (l==3 && wave < 4) {
    #pragma unroll
    for (int kt=0;kt<2;++kt) {
      const float* p = Wa + (size_t)(wave*16 + b)*64 + kt*32 + g4*8;
      float4 lo = *(const float4*)p, hi = *(const float4*)(p+4);
      f16x8 v;
      v[0]=(f16)lo.x; v[1]=(f16)lo.y; v[2]=(f16)lo.z; v[3]=(f16)lo.w;
      v[4]=(f16)hi.x; v[5]=(f16)hi.y; v[6]=(f16)hi.z; v[7]=(f16)hi.w;
      aP[kt]=v;
    }
    float4 bb4 = *(const float4*)(ba + s0);
    cbP[0]=bb4.x; cbP[1]=bb4.y; cbP[2]=bb4.z; cbP[3]=bb4.w;
  }

  // ---- this layer's W frags + bias ----
  f16x8 aW[4][6]; f32x4 cb[4];
  const float* Wl = W + (size_t)l*512*KD;
  #pragma unroll
  for (int q=0;q<4;++q) {
    const float* pr = Wl + (size_t)(128*q + 16*wave + b)*KD + g4*8;
    #pragma unroll
    for (int kt=0;kt<6;++kt) {
      float4 lo = *(const float4*)(pr + kt*32);
      float4 hi = *(const float4*)(pr + kt*32 + 4);
      f16x8 v;
      v[0]=(f16)lo.x; v[1]=(f16)lo.y; v[2]=(f16)lo.z; v[3]=(f16)lo.w;
      v[4]=(f16)hi.x; v[5]=(f16)hi.y; v[6]=(f16)hi.z; v[7]=(f16)hi.w;
      aW[q][kt]=v;
    }
    float4 b4 = *(const float4*)(bias + l*512 + 128*q + s0);
    cb[q][0]=b4.x; cb[q][1]=b4.y; cb[q][2]=b4.z; cb[q][3]=b4.w;
  }

  // ---- init: stage xh(0) = [x0|0|0], prefetch row1 (+skip row0 for l3) ----
  float4 xAf, xBf, skA, skB; f16x4 xAh, xBh;
  if (wave >= 4) {
    f16x4 zz = {(f16)0,(f16)0,(f16)0,(f16)0};
    *(f16x4*)&sxh[0][b*KD + SWZ(b, s0)]    = zz;
    *(f16x4*)&sxh[0][b*KD + SWZ(b, s0+64)] = zz;
  } else {
    if (l>0) {
      #pragma unroll
      for (int w=0;w<4;++w) waitflag(&fIn0[w*pitch + 0], 1u);
    }
    if (l==0) {
      float4 v0 = *(const float4*)(xin + ((size_t)gb)*64 + s0);
      f16x4 h; h[0]=(f16)v0.x; h[1]=(f16)v0.y; h[2]=(f16)v0.z; h[3]=(f16)v0.w;
      *(f16x4*)&sxh[0][b*KD + SWZ(b, s0)] = h;
      xAf = *(const float4*)(xin + ((size_t)256 + gb)*64 + s0);
    } else if (l==2) {
      float4 v0 = *(const float4*)(out + ((size_t)gb)*64 + s0);
      f16x4 h; h[0]=(f16)v0.x; h[1]=(f16)v0.y; h[2]=(f16)v0.z; h[3]=(f16)v0.w;
      *(f16x4*)&sxh[0][b*KD + SWZ(b, s0)] = h;
      xAf = *(const float4*)(out + ((size_t)256 + gb)*64 + s0);
    } else { // l==1 or l==3
      *(f16x4*)&sxh[0][b*KD + SWZ(b, s0)] =
          *(const f16x4*)(ringIn + ((size_t)0*256 + gb)*64 + s0);
      xAh = *(const f16x4*)(ringIn + ((size_t)1*256 + gb)*64 + s0);
      if (l==3) skA = *(const float4*)(out + ((size_t)gb)*64 + s0);
    }
  }
  float cpr[4] = {0.f,0.f,0.f,0.f};
  int idx = 0, ready = 0, consC = 0;
  __syncthreads();

  #pragma unroll 1
  for (int t=0; t<TT; ++t) {
    const int p = t & 1;
    const int idx2 = (idx+1==d) ? 0 : idx+1;

    // ---- B-frag reads of xh(t) (issue LDS early) ----
    f16x8 bx[6];
    const f16* xrow = &sxh[p][b*KD];
    #pragma unroll
    for (int kt=0;kt<6;++kt)
      bx[kt] = *(const f16x8*)&xrow[SWZ(b, kt*32 + g4*8)];

    f16x4 dCv = *(const f16x4*)&scb[(idx*16+b)*128 + SWZ(b, s0)];
    f16x4 dhE;
    if (wave >= 4 && d > 1)
      dhE = *(const f16x4*)&shb[(idx2*16+b)*64 + SWZ(b, s0-64)];

    if (wave < 4) {
      // ---- publish previous group (after-barrier: overlaps waves 4-7) ----
      if (lane==0 && (t&3)==0 && t>0) {
        const int g = (t>>2)-1; const u32 v = (u32)(t>>2);
        if (l<3)          setflag(&myFwd[g], v);
        if (l==1 || l==3) setflag(&myCons[g], v);
      }
      // ---- ring back-pressure (l0,l2) ----
      if ((l==0 || l==2) && (4*consC + 129 < t)) {
        int Ke = ((t-129+3)>>2) + 8; if (Ke > 64) Ke = 64;
        #pragma unroll
        for (int w=0;w<4;++w) waitflag(&cPol0[w*pitch + Ke-1], (u32)Ke);
        consC = Ke;
      }
      // ---- fwd poll, lookahead +6 (polls usually find flag already set) ----
      if (l > 0) {
        int gk = (t+6)>>2; if (gk > 63) gk = 63;
        if (gk > ready) {
          #pragma unroll
          for (int w=0;w<4;++w) waitflag(&fIn0[w*pitch + gk], (u32)(gk+1));
          ready = gk;
        }
      }
      // ---- data prefetch (distance 2) ----
      if (t+2 < TT) {
        if (l==0)      xBf = *(const float4*)(xin + ((size_t)(t+2)*256 + gb)*64 + s0);
        else if (l==2) xBf = *(const float4*)(out + ((size_t)(t+2)*256 + gb)*64 + s0);
        else           xBh = *(const f16x4*)(ringIn + ((size_t)((t+2)&RINGM)*256 + gb)*64 + s0);
      }
      if (l==3 && t+1 < TT) skB = *(const float4*)(out + ((size_t)(t+1)*256 + gb)*64 + s0);
    }

    // ---- fused projection for step t-1 (l==3) ----
    if (l==3 && wave < 4 && t > 0) {
      const f16* fr = &sfin[p^1][b*64];
      f16x8 b0 = *(const f16x8*)&fr[SWZ(b, g4*8)];
      f16x8 b1 = *(const f16x8*)&fr[SWZ(b, 32 + g4*8)];
      f32x4 pa = cbP;
      pa = MFMA16(aP[0], b0, pa);
      pa = MFMA16(aP[1], b1, pa);
      float4 st; st.x=pa[0]; st.y=pa[1]; st.z=pa[2]; st.w=pa[3];
      *(float4*)(out + ((size_t)(t-1)*256 + gb)*64 + s0) = st;
    }

    // ---- gate MFMA: gates = W . xh + bias ----
    f32x4 a0=cb[0], a1=cb[1], a2=cb[2], a3=cb[3];
    #pragma unroll
    for (int kt=0;kt<6;++kt) {
      a0 = MFMA16(aW[0][kt], bx[kt], a0);
      a1 = MFMA16(aW[1][kt], bx[kt], a1);
      a2 = MFMA16(aW[2][kt], bx[kt], a2);
      a3 = MFMA16(aW[3][kt], bx[kt], a3);
    }

    // ---- phase B: in-register LSTM update (4 cells/thread) ----
    float whole[4]; f16x4 ncv;
    #pragma unroll
    for (int r=0;r<4;++r) {
      float f  = sigm(a0[r] + 1.0f);
      float ns = ftanh(a1[r]);
      float al = sigm(a2[r]);
      float o  = sigm(a3[r]);
      float dC = (float)dCv[r];
      float wC = (t>=d) ? fmaf(al, cpr[r]-dC, dC) : cpr[r];
      float nc = (t>0)  ? fmaf(f, wC-ns, ns) : ns;
      whole[r] = o*nc; cpr[r] = nc; ncv[r] = (f16)nc;
    }
    *(f16x4*)&scb[(idx*16+b)*128 + SWZ(b, s0)] = ncv;

    if (wave >= 4) {
      const int jj = s0 - 64;
      f16x4 hv;
      #pragma unroll
      for (int r=0;r<4;++r) hv[r]=(f16)whole[r];
      *(f16x4*)&shb[(idx*16+b)*64 + SWZ(b, jj)] = hv;
      *(f16x4*)&sxh[p^1][b*KD + SWZ(b, s0)] = hv;        // prevH for t+1
      f16x4 dhv = hv;
      if (t+1 >= d && d > 1) dhv = dhE;                  // h_{t+1-d}
      *(f16x4*)&sxh[p^1][b*KD + SWZ(b, s0+64)] = dhv;    // dH for t+1
    } else {
      f16x4 xv;
      if (l==0 || l==2) { xv[0]=(f16)xAf.x; xv[1]=(f16)xAf.y; xv[2]=(f16)xAf.z; xv[3]=(f16)xAf.w; xAf = xBf; }
      else              { xv = xAh; xAh = xBh; }
      *(f16x4*)&sxh[p^1][b*KD + SWZ(b, s0)] = xv;
      if (l==3) {
        f16x4 fv;
        #pragma unroll
        for (int r=0;r<4;++r) fv[r] = (f16)(whole[r] + ((const float*)&skA)[r]);
        *(f16x4*)&sfin[p][b*64 + SWZ(b, s0)] = fv;
        skA = skB;
      } else if (l==1) {
        float4 st; st.x=whole[0]; st.y=whole[1]; st.z=whole[2]; st.w=whole[3];
        *(float4*)(out + ((size_t)t*256 + gb)*64 + s0) = st;   // f32, pre-projection
      } else {
        f16x4 ov;
        #pragma unroll
        for (int r=0;r<4;++r) ov[r]=(f16)whole[r];
        *(f16x4*)(ringOut + ((size_t)(t&RINGM)*256 + gb)*64 + s0) = ov;
      }
    }
    idx = idx2;
    LBAR();   // lgkm-only: xh/fin handoff ordered, vmem stays in flight
  } // t

  // epilogue projection for t = 255 (l==3)
  if (l==3 && wave < 4) {
    const f16* fr = &sfin[1][b*64];
    f16x8 b0 = *(const f16x8*)&fr[SWZ(b, g4*8)];
    f16x8 b1 = *(const f16x8*)&fr[SWZ(b, 32 + g4*8)];
    f32x4 pa = cbP;
    pa = MFMA16(aP[0], b0, pa);
    pa = MFMA16(aP[1], b1, pa);
    float4 st; st.x=pa[0]; st.y=pa[1]; st.z=pa[2]; st.w=pa[3];
    *(float4*)(out + ((size_t)(TT-1)*256 + gb)*64 + s0) = st;
  }

  // final publishes (group 63)
  if (wave < 4 && lane == 0) {
    if (l<3)          setflag(&myFwd[63], 64u);
    if (l==1 || l==3) setflag(&myCons[63], 64u);
  }
}

extern "C" void kernel_launch(void* const* d_in, const int* in_sizes, int n_in,
                              void* d_out, int out_size, void* d_ws, size_t ws_size,
                              hipStream_t stream)
{
  const float* x  = (const float*)d_in[0];
  const float* W  = (const float*)d_in[1];
  const float* bb = (const float*)d_in[2];
  const float* Wa = (const float*)d_in[3];
  const float* ba = (const float*)d_in[4];
  float* out = (float*)d_out;

  f16* bufA  = (f16*)d_ws;                                   // 4 MB ring (l0 out)
  f16* bufC  = (f16*)((char*)d_ws + (4u<<20));               // 4 MB ring (l2 out)
  u32* fwdf  = (u32*)((char*)d_ws + (8u<<20));               // 3*4*16*64 u32 (48 KB)
  u32* consf = (u32*)((char*)d_ws + (8u<<20) + 3*4*16*64*4); // 2*4*16*64 u32 (32 KB)

  hipLaunchKernelGGL(s2_pipe_kernel, dim3(64), dim3(512), 0, stream,
                     x, W, bb, Wa, ba, out, bufA, bufC, fwdf, consf);
}

// Round 10
// 682.539 us; speedup vs baseline: 1.4575x; 1.4575x over previous
//
#include <hip/hip_runtime.h>
#include <cmath>

#define TT 256
#define KD 192
#define RINGM 127   // 128-row ring for bufA/bufC

typedef _Float16 f16;
typedef _Float16 f16x4 __attribute__((ext_vector_type(4)));
typedef _Float16 f16x8 __attribute__((ext_vector_type(8)));
typedef float    f32x4 __attribute__((ext_vector_type(4)));
typedef unsigned int u32;

#define SWZ(b,k) ((k) ^ (((b)&7)<<3))
#define MFMA16(a,bb,c) __builtin_amdgcn_mfma_f32_16x16x32_f16((a),(bb),(c),0,0,0)

__device__ __forceinline__ float sigm(float x){
  return __builtin_amdgcn_rcpf(1.0f + __expf(-x));
}
__device__ __forceinline__ float ftanh(float x){
  x = fminf(15.0f, fmaxf(-15.0f, x));
  float e = __expf(-2.0f*x);
  return (1.0f - e) * __builtin_amdgcn_rcpf(1.0f + e);
}
// tag flags: entry g holds g+1 when ready (g+1 <= 64, never the 0xAA poison)
__device__ __forceinline__ void waitflag(const u32* p, u32 v){
  while (__hip_atomic_load(p, __ATOMIC_ACQUIRE, __HIP_MEMORY_SCOPE_AGENT) != v)
    __builtin_amdgcn_s_sleep(2);
}
__device__ __forceinline__ void setflag(u32* p, u32 v){
  __hip_atomic_store(p, v, __ATOMIC_RELEASE, __HIP_MEMORY_SCOPE_AGENT);
}
// Non-temporal data movement for cross-block dataflow: stores write through
// (never dirty the XCD L2 -> the release fence's L2 writeback finds nothing
// to flush); loads read the coherence point (latency hidden by the existing
// distance-2 prefetch). NOTE: builtins require ext_vector types, not
// HIP_vector_type (float4) -- use f32x4/f16x4.
__device__ __forceinline__ f32x4 ntld4(const float* p){
  return __builtin_nontemporal_load((const f32x4*)p);
}
__device__ __forceinline__ f16x4 ntldh4(const f16* p){
  return __builtin_nontemporal_load((const f16x4*)p);
}
__device__ __forceinline__ void ntst4(float* p, f32x4 v){
  __builtin_nontemporal_store(v, (f32x4*)p);
}
__device__ __forceinline__ void ntsth4(f16* p, f16x4 v){
  __builtin_nontemporal_store(v, (f16x4*)p);
}

// 64 blocks: blockIdx = l*16 + bg (l and l+1 are 16 apart -> same XCD).
// Stage l runs layer l's 256 steps for its 16-batch group.
// l0 -> bufA(ring,f16) -> l1 -> d_out(f32) -> {l2, l3 skip}
// l2 -> bufC(ring,f16) -> l3 -> d_out (fused projection)
extern "C" __global__ void
__attribute__((amdgpu_flat_work_group_size(512,512), amdgpu_waves_per_eu(2,2)))
s2_pipe_kernel(const float* __restrict__ xin, const float* __restrict__ W,
               const float* __restrict__ bias, const float* __restrict__ Wa,
               const float* __restrict__ ba, float* __restrict__ out,
               f16* __restrict__ bufA, f16* __restrict__ bufC,
               u32* __restrict__ fwdf, u32* __restrict__ consf)
{
  const int tid  = threadIdx.x;
  const int wave = tid >> 6;
  const int lane = tid & 63;
  const int b    = lane & 15;
  const int g4   = lane >> 4;
  const int bg   = blockIdx.x & 15;
  const int l    = blockIdx.x >> 4;
  const int gb   = bg*16 + b;
  const int s0   = wave*16 + g4*4;
  const int d    = (l==0)?1:((l==1)?3:((l==2)?6:12));

  __shared__ f16 sxh[2][16*KD];
  __shared__ f16 scb[12*16*128];
  __shared__ f16 shb[12*16*64];
  __shared__ f16 sfin[2][16*64];

  u32* fIn  = fwdf + (((l>0)?(l-1):0)*16 + bg)*64;   // poll (l>0)
  u32* fOut = fwdf + (((l<3)?l:0)*16 + bg)*64;       // publish (l<3)
  u32* cPub = consf + (((l==3)?1:0)*16 + bg)*64;     // publish (l1,l3)
  u32* cPol = consf + (((l==2)?1:0)*16 + bg)*64;     // poll (l0,l2)

  f16* ringOut      = (l==0) ? bufA : bufC;
  const f16* ringIn = (l==1) ? bufA : bufC;

  // ---- projection frags (l==3, waves 0-3) ----
  f16x8 aP[2]; f32x4 cbP;
  if (l==3 && wave < 4) {
    #pragma unroll
    for (int kt=0;kt<2;++kt) {
      const float* p = Wa + (size_t)(wave*16 + b)*64 + kt*32 + g4*8;
      f32x4 lo = *(const f32x4*)p, hi = *(const f32x4*)(p+4);
      f16x8 v;
      v[0]=(f16)lo[0]; v[1]=(f16)lo[1]; v[2]=(f16)lo[2]; v[3]=(f16)lo[3];
      v[4]=(f16)hi[0]; v[5]=(f16)hi[1]; v[6]=(f16)hi[2]; v[7]=(f16)hi[3];
      aP[kt]=v;
    }
    cbP = *(const f32x4*)(ba + s0);
  }

  // ---- this layer's W frags + bias ----
  f16x8 aW[4][6]; f32x4 cb[4];
  const float* Wl = W + (size_t)l*512*KD;
  #pragma unroll
  for (int q=0;q<4;++q) {
    const float* pr = Wl + (size_t)(128*q + 16*wave + b)*KD + g4*8;
    #pragma unroll
    for (int kt=0;kt<6;++kt) {
      f32x4 lo = *(const f32x4*)(pr + kt*32);
      f32x4 hi = *(const f32x4*)(pr + kt*32 + 4);
      f16x8 v;
      v[0]=(f16)lo[0]; v[1]=(f16)lo[1]; v[2]=(f16)lo[2]; v[3]=(f16)lo[3];
      v[4]=(f16)hi[0]; v[5]=(f16)hi[1]; v[6]=(f16)hi[2]; v[7]=(f16)hi[3];
      aW[q][kt]=v;
    }
    cb[q] = *(const f32x4*)(bias + l*512 + 128*q + s0);
  }

  // ---- init: stage xh(0) = [x0|0|0], prefetch row1 (+skip row0 for l3) ----
  f32x4 xAf, xBf, skA, skB; f16x4 xAh, xBh;
  if (wave >= 4) {
    f16x4 zz = {(f16)0,(f16)0,(f16)0,(f16)0};
    *(f16x4*)&sxh[0][b*KD + SWZ(b, s0)]    = zz;
    *(f16x4*)&sxh[0][b*KD + SWZ(b, s0+64)] = zz;
  } else {
    if (l>0) waitflag(&fIn[0], 1u);      // producer rows 0-3 ready
    if (l==0) {
      f32x4 v0 = *(const f32x4*)(xin + ((size_t)gb)*64 + s0);
      f16x4 h; h[0]=(f16)v0[0]; h[1]=(f16)v0[1]; h[2]=(f16)v0[2]; h[3]=(f16)v0[3];
      *(f16x4*)&sxh[0][b*KD + SWZ(b, s0)] = h;
      xAf = *(const f32x4*)(xin + ((size_t)256 + gb)*64 + s0);
    } else if (l==2) {
      f32x4 v0 = ntld4(out + ((size_t)gb)*64 + s0);
      f16x4 h; h[0]=(f16)v0[0]; h[1]=(f16)v0[1]; h[2]=(f16)v0[2]; h[3]=(f16)v0[3];
      *(f16x4*)&sxh[0][b*KD + SWZ(b, s0)] = h;
      xAf = ntld4(out + ((size_t)256 + gb)*64 + s0);
    } else { // l==1 or l==3
      *(f16x4*)&sxh[0][b*KD + SWZ(b, s0)] =
          ntldh4(ringIn + ((size_t)0*256 + gb)*64 + s0);
      xAh = ntldh4(ringIn + ((size_t)1*256 + gb)*64 + s0);
      if (l==3) skA = ntld4(out + ((size_t)gb)*64 + s0);
    }
  }
  float cpr[4] = {0.f,0.f,0.f,0.f};
  int idx = 0, ready = 0, consC = 0;
  __syncthreads();

  #pragma unroll 1
  for (int t=0; t<TT; ++t) {
    const int p = t & 1;
    const int idx2 = (idx+1==d) ? 0 : idx+1;

    // ---- B-frag reads of xh(t) ----
    f16x8 bx[6];
    const f16* xrow = &sxh[p][b*KD];
    #pragma unroll
    for (int kt=0;kt<6;++kt)
      bx[kt] = *(const f16x8*)&xrow[SWZ(b, kt*32 + g4*8)];

    // ---- early LDS reads (hide under MFMA) ----
    f16x4 dCv = *(const f16x4*)&scb[(idx*16+b)*128 + SWZ(b, s0)];
    f16x4 dhE;
    if (wave >= 4 && d > 1)
      dhE = *(const f16x4*)&shb[(idx2*16+b)*64 + SWZ(b, s0-64)];

    if (wave < 4) {
      // ---- ring back-pressure (l0,l2) ----
      if ((l==0 || l==2) && (4*consC + 129 < t)) {
        int Ke = ((t-129+3)>>2) + 8; if (Ke > 64) Ke = 64;
        waitflag(&cPol[Ke-1], (u32)Ke);
        consC = Ke;
      }
      // ---- fwd poll + data prefetch (distance 2) ----
      if (t+2 < TT) {
        int nc = (t+2) >> 2;
        if (l > 0 && nc > ready) { waitflag(&fIn[nc], (u32)(nc+1)); ready = nc; }
        if (l==0)      xBf = *(const f32x4*)(xin + ((size_t)(t+2)*256 + gb)*64 + s0);
        else if (l==2) xBf = ntld4(out + ((size_t)(t+2)*256 + gb)*64 + s0);
        else           xBh = ntldh4(ringIn + ((size_t)((t+2)&RINGM)*256 + gb)*64 + s0);
      }
      if (l==3 && t+1 < TT) skB = ntld4(out + ((size_t)(t+1)*256 + gb)*64 + s0);
    }

    // ---- fused projection for step t-1 (l==3) ----
    if (l==3 && wave < 4 && t > 0) {
      const f16* fr = &sfin[p^1][b*64];
      f16x8 b0 = *(const f16x8*)&fr[SWZ(b, g4*8)];
      f16x8 b1 = *(const f16x8*)&fr[SWZ(b, 32 + g4*8)];
      f32x4 pa = cbP;
      pa = MFMA16(aP[0], b0, pa);
      pa = MFMA16(aP[1], b1, pa);
      ntst4(out + ((size_t)(t-1)*256 + gb)*64 + s0, pa);
    }

    // ---- gate MFMA: gates = W . xh + bias ----
    f32x4 a0=cb[0], a1=cb[1], a2=cb[2], a3=cb[3];
    #pragma unroll
    for (int kt=0;kt<6;++kt) {
      a0 = MFMA16(aW[0][kt], bx[kt], a0);
      a1 = MFMA16(aW[1][kt], bx[kt], a1);
      a2 = MFMA16(aW[2][kt], bx[kt], a2);
      a3 = MFMA16(aW[3][kt], bx[kt], a3);
    }

    // ---- phase B: in-register LSTM update (4 cells/thread) ----
    float whole[4]; f16x4 ncv;
    #pragma unroll
    for (int r=0;r<4;++r) {
      float f  = sigm(a0[r] + 1.0f);
      float ns = ftanh(a1[r]);
      float al = sigm(a2[r]);
      float o  = sigm(a3[r]);
      float dC = (float)dCv[r];
      float wC = (t>=d) ? fmaf(al, cpr[r]-dC, dC) : cpr[r];
      float nc = (t>0)  ? fmaf(f, wC-ns, ns) : ns;
      whole[r] = o*nc; cpr[r] = nc; ncv[r] = (f16)nc;
    }
    *(f16x4*)&scb[(idx*16+b)*128 + SWZ(b, s0)] = ncv;

    if (wave >= 4) {
      const int jj = s0 - 64;
      f16x4 hv;
      #pragma unroll
      for (int r=0;r<4;++r) hv[r]=(f16)whole[r];
      *(f16x4*)&shb[(idx*16+b)*64 + SWZ(b, jj)] = hv;
      *(f16x4*)&sxh[p^1][b*KD + SWZ(b, s0)] = hv;        // prevH for t+1
      f16x4 dhv = hv;
      if (t+1 >= d && d > 1) dhv = dhE;                  // h_{t+1-d}
      *(f16x4*)&sxh[p^1][b*KD + SWZ(b, s0+64)] = dhv;    // dH for t+1
    } else {
      f16x4 xv;
      if (l==0 || l==2) { xv[0]=(f16)xAf[0]; xv[1]=(f16)xAf[1]; xv[2]=(f16)xAf[2]; xv[3]=(f16)xAf[3]; xAf = xBf; }
      else              { xv = xAh; xAh = xBh; }
      *(f16x4*)&sxh[p^1][b*KD + SWZ(b, s0)] = xv;
      if (l==3) {
        f16x4 fv;
        #pragma unroll
        for (int r=0;r<4;++r) fv[r] = (f16)(whole[r] + skA[r]);
        *(f16x4*)&sfin[p][b*64 + SWZ(b, s0)] = fv;
        skA = skB;
      } else if (l==1) {
        f32x4 st; st[0]=whole[0]; st[1]=whole[1]; st[2]=whole[2]; st[3]=whole[3];
        ntst4(out + ((size_t)t*256 + gb)*64 + s0, st);   // f32, pre-projection
      } else {
        f16x4 ov;
        #pragma unroll
        for (int r=0;r<4;++r) ov[r]=(f16)whole[r];
        ntsth4(ringOut + ((size_t)(t&RINGM)*256 + gb)*64 + s0, ov);
      }
    }
    idx = idx2;
    __syncthreads();   // drains stores (vmcnt0) -> safe to publish

    if ((t&3)==3 && tid==0) {
      if (l<3)            setflag(&fOut[t>>2], (u32)((t>>2)+1));  // rows<=t ready
      if (l==1 || l==3)   setflag(&cPub[t>>2], (u32)((t>>2)+1));  // ring consumed
    }
  } // t

  // epilogue projection for t = 255 (l==3)
  if (l==3 && wave < 4) {
    const f16* fr = &sfin[1][b*64];
    f16x8 b0 = *(const f16x8*)&fr[SWZ(b, g4*8)];
    f16x8 b1 = *(const f16x8*)&fr[SWZ(b, 32 + g4*8)];
    f32x4 pa = cbP;
    pa = MFMA16(aP[0], b0, pa);
    pa = MFMA16(aP[1], b1, pa);
    ntst4(out + ((size_t)(TT-1)*256 + gb)*64 + s0, pa);
  }
}

extern "C" void kernel_launch(void* const* d_in, const int* in_sizes, int n_in,
                              void* d_out, int out_size, void* d_ws, size_t ws_size,
                              hipStream_t stream)
{
  const float* x  = (const float*)d_in[0];
  const float* W  = (const float*)d_in[1];
  const float* bb = (const float*)d_in[2];
  const float* Wa = (const float*)d_in[3];
  const float* ba = (const float*)d_in[4];
  float* out = (float*)d_out;

  f16* bufA  = (f16*)d_ws;                                   // 4 MB ring (l0 out)
  f16* bufC  = (f16*)((char*)d_ws + (4u<<20));               // 4 MB ring (l2 out)
  u32* fwdf  = (u32*)((char*)d_ws + (8u<<20));               // 3*16*64 u32
  u32* consf = (u32*)((char*)d_ws + (8u<<20) + 3*16*64*4);   // 2*16*64 u32

  hipLaunchKernelGGL(s2_pipe_kernel, dim3(64), dim3(512), 0, stream,
                     x, W, bb, Wa, ba, out, bufA, bufC, fwdf, consf);
}